// Round 14
// baseline (530.988 us; speedup 1.0000x reference)
//
#include <hip/hip_runtime.h>

#define N_ATOMS 100000
#define N_PAIRS 1600000
#define F_A 75
#define F_P 14
#define H 50

#define PROJ_BLOCKS (N_ATOMS / 32)   // 3125
#define SEG_BLOCKS  (N_ATOMS / 4)    // 25000
#define PO_BLOCKS   2048
#define AOUT_BLOCKS (N_ATOMS / 32)   // 3125

typedef float f32x2 __attribute__((ext_vector_type(2)));
typedef float f32x4 __attribute__((ext_vector_type(4)));
typedef short bf16x8 __attribute__((ext_vector_type(8)));
typedef unsigned u32x4 __attribute__((ext_vector_type(4)));

__device__ inline unsigned short f2bf(float f) {
    unsigned u = __float_as_uint(f);
    u += 0x7fffu + ((u >> 16) & 1u);
    return (unsigned short)(u >> 16);
}
__device__ inline float bfu(unsigned u, int hi) {
    return __uint_as_float(hi ? (u & 0xffff0000u) : (u << 16));
}

// asm gather: pinned issue point, regalloc cannot sink or rematerialize it.
#define GLOAD16(dst, ptr) \
    asm volatile("global_load_dwordx4 %0, %1, off" : "=v"(dst) : "v"(ptr))

// ---------------- kernel 0: row_start[a] = lower_bound(split, a) ----------------
__global__ __launch_bounds__(256) void k_row_starts(
    const int* __restrict__ split, int* __restrict__ row_start)
{
    int p = blockIdx.x * 256 + threadIdx.x;
    if (p >= N_PAIRS) return;
    int s = split[p];
    int sp = (p == 0) ? -1 : split[p - 1];
    for (int a = sp + 1; a <= s; ++a) row_start[a] = p;
    if (p == N_PAIRS - 1)
        for (int a = s + 1; a <= N_ATOMS; ++a) row_start[a] = N_PAIRS;
}

// ================= stage 1 (fat, ZERO LDS): atom_proj || pa_segsum =================
__global__ __launch_bounds__(256) void k_stage1(
    const float* __restrict__ af, const float* __restrict__ W_AA,
    const float* __restrict__ b_AA, const float* __restrict__ W_AP,
    const float* __restrict__ b_AP,
    const float* __restrict__ pf, const int* __restrict__ row_start,
    const float* __restrict__ W_PA, const float* __restrict__ b_PA,
    float* __restrict__ AA, unsigned short* __restrict__ X,
    float* __restrict__ PA)
{
    const int wave = __builtin_amdgcn_readfirstlane(threadIdx.x >> 6);
    const int lane = threadIdx.x & 63;
    const int h = lane < H ? lane : 0;

    if (blockIdx.x < PROJ_BLOCKS) {
        const int base = blockIdx.x * 32 + wave * 8;
        const float bAA = b_AA[h];
        const float bAP = (lane < H) ? b_AP[lane] : 0.f;

        float aa[8], x1[8], x2[8];
        #pragma unroll
        for (int a = 0; a < 8; ++a) { aa[a] = bAA; x1[a] = 0.f; x2[a] = 0.f; }

        for (int c0 = 0; c0 < 72; c0 += 4) {
            f32x4 fv[8];
            #pragma unroll
            for (int a = 0; a < 8; ++a)
                fv[a] = *(const f32x4*)(af + (size_t)(base + a) * F_A + c0);
            #pragma unroll
            for (int cc = 0; cc < 4; ++cc) {
                int c = c0 + cc;
                float waa = W_AA[c * H + h];
                float w1  = W_AP[c * H + h];
                float w2  = W_AP[(F_A + c) * H + h];
                #pragma unroll
                for (int a = 0; a < 8; ++a) {
                    float f = fv[a][cc];
                    aa[a] = fmaf(f, waa, aa[a]);
                    x1[a] = fmaf(f, w1, x1[a]);
                    x2[a] = fmaf(f, w2, x2[a]);
                }
            }
        }
        #pragma unroll
        for (int c = 72; c < F_A; ++c) {
            float waa = W_AA[c * H + h];
            float w1  = W_AP[c * H + h];
            float w2  = W_AP[(F_A + c) * H + h];
            #pragma unroll
            for (int a = 0; a < 8; ++a) {
                float f = af[(size_t)(base + a) * F_A + c];
                aa[a] = fmaf(f, waa, aa[a]);
                x1[a] = fmaf(f, w1, x1[a]);
                x2[a] = fmaf(f, w2, x2[a]);
            }
        }
        #pragma unroll
        for (int a = 0; a < 8; ++a) {
            int atom = base + a;
            if (lane < H) AA[(size_t)atom * H + lane] = fmaxf(aa[a], 0.f);
            unsigned short v1 = (lane < H) ? f2bf(x1[a] + bAP) : (unsigned short)0;
            unsigned short v2 = (lane < H) ? f2bf(x2[a]) : (unsigned short)0;
            unsigned short* Xrow = X + (size_t)atom * 128;
            Xrow[lane]      = v1;
            Xrow[64 + lane] = v2;
        }
    } else {
        const int atom = (blockIdx.x - PROJ_BLOCKS) * 4 + wave;

        float w[F_P];
        #pragma unroll
        for (int c = 0; c < F_P; ++c) w[c] = W_PA[c * H + h];
        const float bias = b_PA[h];

        const int start = row_start[atom];
        const int end   = row_start[atom + 1];

        float acc = 0.f;
        int p = start;
        for (; p + 4 <= end; p += 4) {
            f32x2 v[4][7];
            #pragma unroll
            for (int r = 0; r < 4; ++r) {
                const f32x2* src = (const f32x2*)(pf + (size_t)(p + r) * F_P);
                #pragma unroll
                for (int c = 0; c < 7; ++c) v[r][c] = __builtin_nontemporal_load(src + c);
            }
            #pragma unroll
            for (int r = 0; r < 4; ++r) {
                float s0 = bias;
                #pragma unroll
                for (int c = 0; c < 7; ++c) {
                    s0 = fmaf(v[r][c].x, w[2*c], s0);
                    s0 = fmaf(v[r][c].y, w[2*c+1], s0);
                }
                acc += fmaxf(s0, 0.f);
            }
        }
        for (; p < end; ++p) {
            const f32x2* src = (const f32x2*)(pf + (size_t)p * F_P);
            float s0 = bias;
            #pragma unroll
            for (int c = 0; c < 7; ++c) {
                f32x2 v = __builtin_nontemporal_load(src + c);
                s0 = fmaf(v.x, w[2*c], s0); s0 = fmaf(v.y, w[2*c+1], s0);
            }
            acc += fmaxf(s0, 0.f);
        }
        if (lane < H) PA[(size_t)atom * H + lane] = acc;
    }
}

// ================= stage 2 (fat): pair_out (MFMA, asm-pinned rolling prefetch) || atom_out =================
__global__ __launch_bounds__(256, 4) void k_stage2(
    const float* __restrict__ pf, const int* __restrict__ a2p,
    const unsigned short* __restrict__ X,
    const float* __restrict__ W_PP, const float* __restrict__ b_PP,
    const float* __restrict__ W_P, const float* __restrict__ b_P,
    const float* __restrict__ AA, const float* __restrict__ PA,
    const float* __restrict__ W_A, const float* __restrict__ b_A,
    float* __restrict__ outA, float* __restrict__ outP)
{
    __shared__ __align__(16) char smem[26624];

    const int tid  = threadIdx.x;
    const int wave = __builtin_amdgcn_readfirstlane(tid >> 6);
    const int lane = tid & 63;

    if (blockIdx.x < PO_BLOCKS) {
        uint4* sWf = (uint4*)smem;                                // 16 KB
        float (*sWPP)[64] = (float(*)[64])(smem + 16384);         // 3.5 KB
        float* sbPP = (float*)(smem + 16384 + 3584);              // 256 B
        float* sT   = (float*)(smem + 16384 + 3584 + 256);        // 6.4 KB

        // build B-frags (R3-validated): lane holds col=lane&15, k = s*32+(lane>>4)*8+[0..7]
        #pragma unroll
        for (int r = 0; r < 4; ++r) {
            int e = r * 256 + tid;
            int fid = e >> 6, lane_e = e & 63;
            int s_ = fid >> 2, n_ = fid & 3;
            int col_e = lane_e & 15, gg = lane_e >> 4;
            int k0 = s_ * 32 + gg * 8;
            int c = n_ * 16 + col_e;
            unsigned w[4];
            #pragma unroll
            for (int hh = 0; hh < 4; ++hh) {
                float vlo = 0.f, vhi = 0.f;
                if (c < H) {
                    int k = k0 + 2 * hh;
                    int r0 = (k < 64) ? (k < H ? k : -1) : ((k - 64) < H ? H + (k - 64) : -1);
                    int k2 = k + 1;
                    int r1 = (k2 < 64) ? (k2 < H ? k2 : -1) : ((k2 - 64) < H ? H + (k2 - 64) : -1);
                    if (r0 >= 0) vlo = W_P[r0 * H + c];
                    if (r1 >= 0) vhi = W_P[r1 * H + c];
                }
                w[hh] = (unsigned)f2bf(vlo) | ((unsigned)f2bf(vhi) << 16);
            }
            sWf[e] = make_uint4(w[0], w[1], w[2], w[3]);
        }
        for (int t = tid; t < F_P * 64; t += 256) {
            int c = t >> 6, o = t & 63;
            sWPP[c][o] = (o < H) ? W_PP[c * H + o] : 0.f;
        }
        if (tid < 64) sbPP[tid] = tid < H ? b_PP[tid] : 0.f;
        __syncthreads();

        const int col = lane & 15;
        const int g = lane >> 4;
        float* const myT = sT + wave * 400;

        float bP[4];
        #pragma unroll
        for (int n = 0; n < 4; ++n) {
            int c = n * 16 + col;
            bP[n] = (c < H) ? b_P[c] : 0.f;
        }

        const int NT = N_PAIRS / 16;     // 100000 tiles
        const int step = PO_BLOCKS * 4;  // 8192
        const int off0 = g * 8, off1 = 32 + g * 8;

        int t = blockIdx.x * 4 + wave;   // always < step <= NT
        int t1 = t + step;

        // ---- prologue: asm-issue tile t's gathers + pfr; prefetch ijN ----
        u32x4 A1a, A1b, B2a, B2b, B1a, B1b, A2a, A2b;
        {
            int2 ij0 = ((const int2*)a2p)[t * 16 + col];
            const unsigned short* Xi = X + (size_t)ij0.x * 128;
            const unsigned short* Xj = X + (size_t)ij0.y * 128;
            GLOAD16(A1a, Xi + off0);      GLOAD16(A1b, Xi + off1);
            GLOAD16(B2a, Xj + 64 + off0); GLOAD16(B2b, Xj + 64 + off1);
            GLOAD16(B1a, Xj + off0);      GLOAD16(B1b, Xj + off1);
            GLOAD16(A2a, Xi + 64 + off0); GLOAD16(A2b, Xi + 64 + off1);
        }
        f32x2 pfrN[7];
        {
            const f32x2* src = (const f32x2*)(pf + (size_t)(t * 16 + col) * F_P);
            #pragma unroll
            for (int c = 0; c < 7; ++c) pfrN[c] = __builtin_nontemporal_load(src + c);
        }
        int2 ijN = make_int2(0, 0);
        if (t1 < NT) ijN = ((const int2*)a2p)[t1 * 16 + col];

        while (true) {
            const int pairbase = t * 16;
            const bool haveNext = (t1 < NT);

            // ---- wait for tile t's gathers (and pfr) to land; pin ordering ----
            asm volatile("s_waitcnt vmcnt(0)" ::: "memory");
            __builtin_amdgcn_sched_barrier(0);

            // ---- convert landed X(t) into 2 bf16 A-frags (frees the gather regs) ----
            union { unsigned u[4]; bf16x8 v; } apA[2];
            {
                const u32x4* g1[2] = { &A1a, &A1b };
                const u32x4* g2[2] = { &B2a, &B2b };
                const u32x4* g3[2] = { &B1a, &B1b };
                const u32x4* g4[2] = { &A2a, &A2b };
                #pragma unroll
                for (int s = 0; s < 2; ++s) {
                    #pragma unroll
                    for (int hh = 0; hh < 4; ++hh) {
                        unsigned ua1 = (*g1[s])[hh], ub2 = (*g2[s])[hh];
                        unsigned ub1 = (*g3[s])[hh], ua2 = (*g4[s])[hh];
                        float e1l = bfu(ua1,0) + bfu(ub2,0);
                        float e2l = bfu(ub1,0) + bfu(ua2,0);
                        float apl = fmaxf(e1l, 0.f) + fmaxf(e2l, 0.f);
                        float e1h = bfu(ua1,1) + bfu(ub2,1);
                        float e2h = bfu(ub1,1) + bfu(ua2,1);
                        float aph = fmaxf(e1h, 0.f) + fmaxf(e2h, 0.f);
                        apA[s].u[hh] = (unsigned)f2bf(apl) | ((unsigned)f2bf(aph) << 16);
                    }
                }
            }
            f32x2 pfrC[7];
            #pragma unroll
            for (int c = 0; c < 7; ++c) pfrC[c] = pfrN[c];

            // ---- asm-issue tile t+1's gathers (pinned; cannot sink) + plain pfr/ij ----
            int t2 = t1 + step;
            int2 ij2 = ijN;
            if (haveNext) {
                const unsigned short* Xi = X + (size_t)ijN.x * 128;
                const unsigned short* Xj = X + (size_t)ijN.y * 128;
                GLOAD16(A1a, Xi + off0);      GLOAD16(A1b, Xi + off1);
                GLOAD16(B2a, Xj + 64 + off0); GLOAD16(B2b, Xj + 64 + off1);
                GLOAD16(B1a, Xj + off0);      GLOAD16(B1b, Xj + off1);
                GLOAD16(A2a, Xi + 64 + off0); GLOAD16(A2b, Xi + 64 + off1);
                const f32x2* src = (const f32x2*)(pf + (size_t)(t1 * 16 + col) * F_P);
                #pragma unroll
                for (int c = 0; c < 7; ++c) pfrN[c] = __builtin_nontemporal_load(src + c);
                if (t2 < NT) ij2 = ((const int2*)a2p)[t2 * 16 + col];
            }
            __builtin_amdgcn_sched_barrier(0);   // keep compute below the issue cluster

            // ---- compute tile t ----
            f32x4 acc[4];
            #pragma unroll
            for (int n = 0; n < 4; ++n) acc[n] = (f32x4){bP[n], bP[n], bP[n], bP[n]};

            // AP K-steps (global k = 0..63); b_AP pre-folded into X1
            #pragma unroll
            for (int s = 0; s < 2; ++s) {
                #pragma unroll
                for (int n = 0; n < 4; ++n) {
                    bf16x8 bfr = ((const bf16x8*)sWf)[(s * 4 + n) * 64 + lane];
                    acc[n] = __builtin_amdgcn_mfma_f32_16x16x32_bf16(apA[s].v, bfr, acc[n], 0, 0, 0);
                }
            }

            // PP K-steps (global k = 64..127)
            #pragma unroll
            for (int s2 = 0; s2 < 2; ++s2) {
                int ob = s2 * 32 + g * 8;
                float pp[8];
                {
                    const f32x4* bb = (const f32x4*)&sbPP[ob];
                    f32x4 b0 = bb[0], b1 = bb[1];
                    pp[0]=b0.x; pp[1]=b0.y; pp[2]=b0.z; pp[3]=b0.w;
                    pp[4]=b1.x; pp[5]=b1.y; pp[6]=b1.z; pp[7]=b1.w;
                }
                #pragma unroll
                for (int c = 0; c < F_P; ++c) {
                    const f32x4* wr = (const f32x4*)&sWPP[c][ob];
                    f32x4 w0 = wr[0], w1 = wr[1];
                    float pc = (c & 1) ? pfrC[c >> 1].y : pfrC[c >> 1].x;
                    pp[0]=fmaf(pc,w0.x,pp[0]); pp[1]=fmaf(pc,w0.y,pp[1]);
                    pp[2]=fmaf(pc,w0.z,pp[2]); pp[3]=fmaf(pc,w0.w,pp[3]);
                    pp[4]=fmaf(pc,w1.x,pp[4]); pp[5]=fmaf(pc,w1.y,pp[5]);
                    pp[6]=fmaf(pc,w1.z,pp[6]); pp[7]=fmaf(pc,w1.w,pp[7]);
                }
                union { unsigned u[4]; bf16x8 v; } ap;
                #pragma unroll
                for (int hh = 0; hh < 4; ++hh) {
                    float lo = fmaxf(pp[2*hh], 0.f), hi2 = fmaxf(pp[2*hh+1], 0.f);
                    ap.u[hh] = (unsigned)f2bf(lo) | ((unsigned)f2bf(hi2) << 16);
                }
                int sg = 2 + s2;
                #pragma unroll
                for (int n = 0; n < 4; ++n) {
                    bf16x8 bfr = ((const bf16x8*)sWf)[(sg * 4 + n) * 64 + lane];
                    acc[n] = __builtin_amdgcn_mfma_f32_16x16x32_bf16(ap.v, bfr, acc[n], 0, 0, 0);
                }
            }

            // ---- two-phase epilogue: rows 0..7 then 8..15 via 400-float wave buffer ----
            float* dst = outP + (size_t)pairbase * H;
            if (g < 2) {
                #pragma unroll
                for (int n = 0; n < 4; ++n) {
                    int c = n * 16 + col;
                    if (c < H) {
                        #pragma unroll
                        for (int q = 0; q < 4; ++q)
                            myT[(g * 4 + q) * H + c] = fmaxf(acc[n][q], 0.f);
                    }
                }
            }
            #pragma unroll
            for (int e = 0; e < 4; ++e) {
                int idx = e * 64 + lane;            // f32x2 idx, 200 total
                if (idx < 200) {
                    f32x2 v = *(const f32x2*)&myT[idx * 2];
                    *(f32x2*)(dst + idx * 2) = v;
                }
            }
            if (g >= 2) {
                #pragma unroll
                for (int n = 0; n < 4; ++n) {
                    int c = n * 16 + col;
                    if (c < H) {
                        #pragma unroll
                        for (int q = 0; q < 4; ++q)
                            myT[((g - 2) * 4 + q) * H + c] = fmaxf(acc[n][q], 0.f);
                    }
                }
            }
            #pragma unroll
            for (int e = 0; e < 4; ++e) {
                int idx = e * 64 + lane;
                if (idx < 200) {
                    f32x2 v = *(const f32x2*)&myT[idx * 2];
                    *(f32x2*)(dst + 400 + idx * 2) = v;
                }
            }

            if (!haveNext) break;
            t = t1; t1 = t2; ijN = ij2;
        }
    } else {
        // ---------------- atom_out ----------------
        float* sW = (float*)smem;            // 20 KB
        float* sb = (float*)(smem + 20000);  // 200 B
        for (int t = tid; t < 2 * H * H; t += 256) sW[t] = W_A[t];
        if (tid < H) sb[tid] = b_A[tid];
        __syncthreads();

        const int h = lane < H ? lane : 0;
        const int base = (blockIdx.x - PO_BLOCKS) * 32 + wave * 8;

        float acc[8];
        #pragma unroll
        for (int a = 0; a < 8; ++a) acc[a] = sb[h];

        for (int k = 0; k < H; ++k) {
            float wA = sW[k * H + h];
            float wP = sW[(H + k) * H + h];
            #pragma unroll
            for (int a = 0; a < 8; ++a) {
                acc[a] = fmaf(AA[(size_t)(base + a) * H + k], wA, acc[a]);
                acc[a] = fmaf(PA[(size_t)(base + a) * H + k], wP, acc[a]);
            }
        }
        #pragma unroll
        for (int a = 0; a < 8; ++a)
            if (lane < H) outA[(size_t)(base + a) * H + lane] = fmaxf(acc[a], 0.f);
    }
}

// ---------------- launcher ----------------
extern "C" void kernel_launch(void* const* d_in, const int* in_sizes, int n_in,
                              void* d_out, int out_size, void* d_ws, size_t ws_size,
                              hipStream_t stream) {
    const float* af    = (const float*)d_in[0];
    const float* pfeat = (const float*)d_in[1];
    const int*   split = (const int*)d_in[2];
    const int*   a2p   = (const int*)d_in[3];
    const float* W_AA  = (const float*)d_in[4];
    const float* b_AA  = (const float*)d_in[5];
    const float* W_PA  = (const float*)d_in[6];
    const float* b_PA  = (const float*)d_in[7];
    const float* W_A   = (const float*)d_in[8];
    const float* b_A   = (const float*)d_in[9];
    const float* W_AP  = (const float*)d_in[10];
    const float* b_AP  = (const float*)d_in[11];
    const float* W_PP  = (const float*)d_in[12];
    const float* b_PP  = (const float*)d_in[13];
    const float* W_P   = (const float*)d_in[14];
    const float* b_P   = (const float*)d_in[15];

    float* outA = (float*)d_out;
    float* outP = (float*)d_out + (size_t)N_ATOMS * H;

    unsigned short* X  = (unsigned short*)d_ws;               // 25.6 MB
    float* AA          = (float*)(X + (size_t)N_ATOMS * 128); // 20 MB
    float* PA          = AA + (size_t)N_ATOMS * H;            // 20 MB
    int*   row_start   = (int*)(PA + (size_t)N_ATOMS * H);    // (N_ATOMS+1)*4B

    k_row_starts<<<(N_PAIRS + 255) / 256, 256, 0, stream>>>(split, row_start);
    k_stage1<<<PROJ_BLOCKS + SEG_BLOCKS, 256, 0, stream>>>(
        af, W_AA, b_AA, W_AP, b_AP, pfeat, row_start, W_PA, b_PA, AA, X, PA);
    k_stage2<<<PO_BLOCKS + AOUT_BLOCKS, 256, 0, stream>>>(
        pfeat, a2p, X, W_PP, b_PP, W_P, b_P, AA, PA, W_A, b_A, outA, outP);
}

// Round 16
// 504.373 us; speedup vs baseline: 1.0528x; 1.0528x over previous
//
#include <hip/hip_runtime.h>

#define N_ATOMS 100000
#define N_PAIRS 1600000
#define F_A 75
#define F_P 14
#define H 50

#define PROJ_BLOCKS (N_ATOMS / 32)   // 3125
#define SEG_BLOCKS  (N_ATOMS / 4)    // 25000
#define PO_BLOCKS   2048
#define AOUT_BLOCKS (N_ATOMS / 32)   // 3125

typedef float f32x2 __attribute__((ext_vector_type(2)));
typedef float f32x4 __attribute__((ext_vector_type(4)));
typedef short bf16x8 __attribute__((ext_vector_type(8)));

__device__ inline unsigned short f2bf(float f) {
    unsigned u = __float_as_uint(f);
    u += 0x7fffu + ((u >> 16) & 1u);
    return (unsigned short)(u >> 16);
}
__device__ inline float bfu(unsigned u, int hi) {
    return __uint_as_float(hi ? (u & 0xffff0000u) : (u << 16));
}

// ---------------- kernel 0: row_start[a] = lower_bound(split, a) ----------------
__global__ __launch_bounds__(256) void k_row_starts(
    const int* __restrict__ split, int* __restrict__ row_start)
{
    int p = blockIdx.x * 256 + threadIdx.x;
    if (p >= N_PAIRS) return;
    int s = split[p];
    int sp = (p == 0) ? -1 : split[p - 1];
    for (int a = sp + 1; a <= s; ++a) row_start[a] = p;
    if (p == N_PAIRS - 1)
        for (int a = s + 1; a <= N_ATOMS; ++a) row_start[a] = N_PAIRS;
}

// ================= stage 1 (fat, ZERO LDS): atom_proj || pa_segsum =================
__global__ __launch_bounds__(256) void k_stage1(
    const float* __restrict__ af, const float* __restrict__ W_AA,
    const float* __restrict__ b_AA, const float* __restrict__ W_AP,
    const float* __restrict__ b_AP,
    const float* __restrict__ pf, const int* __restrict__ row_start,
    const float* __restrict__ W_PA, const float* __restrict__ b_PA,
    float* __restrict__ AA, unsigned short* __restrict__ X,
    float* __restrict__ PA)
{
    const int wave = __builtin_amdgcn_readfirstlane(threadIdx.x >> 6);
    const int lane = threadIdx.x & 63;
    const int h = lane < H ? lane : 0;

    if (blockIdx.x < PROJ_BLOCKS) {
        const int base = blockIdx.x * 32 + wave * 8;
        const float bAA = b_AA[h];
        const float bAP = (lane < H) ? b_AP[lane] : 0.f;

        float aa[8], x1[8], x2[8];
        #pragma unroll
        for (int a = 0; a < 8; ++a) { aa[a] = bAA; x1[a] = 0.f; x2[a] = 0.f; }

        // chunk-4 column loop: af rows fetched as wave-uniform dwordx4
        for (int c0 = 0; c0 < 72; c0 += 4) {
            f32x4 fv[8];
            #pragma unroll
            for (int a = 0; a < 8; ++a)
                fv[a] = *(const f32x4*)(af + (size_t)(base + a) * F_A + c0);
            #pragma unroll
            for (int cc = 0; cc < 4; ++cc) {
                int c = c0 + cc;
                float waa = W_AA[c * H + h];
                float w1  = W_AP[c * H + h];
                float w2  = W_AP[(F_A + c) * H + h];
                #pragma unroll
                for (int a = 0; a < 8; ++a) {
                    float f = fv[a][cc];
                    aa[a] = fmaf(f, waa, aa[a]);
                    x1[a] = fmaf(f, w1, x1[a]);
                    x2[a] = fmaf(f, w2, x2[a]);
                }
            }
        }
        #pragma unroll
        for (int c = 72; c < F_A; ++c) {   // tail 3 columns
            float waa = W_AA[c * H + h];
            float w1  = W_AP[c * H + h];
            float w2  = W_AP[(F_A + c) * H + h];
            #pragma unroll
            for (int a = 0; a < 8; ++a) {
                float f = af[(size_t)(base + a) * F_A + c];
                aa[a] = fmaf(f, waa, aa[a]);
                x1[a] = fmaf(f, w1, x1[a]);
                x2[a] = fmaf(f, w2, x2[a]);
            }
        }
        #pragma unroll
        for (int a = 0; a < 8; ++a) {
            int atom = base + a;
            if (lane < H) AA[(size_t)atom * H + lane] = fmaxf(aa[a], 0.f);
            unsigned short v1 = (lane < H) ? f2bf(x1[a] + bAP) : (unsigned short)0;
            unsigned short v2 = (lane < H) ? f2bf(x2[a]) : (unsigned short)0;
            unsigned short* Xrow = X + (size_t)atom * 128;
            Xrow[lane]      = v1;
            Xrow[64 + lane] = v2;
        }
    } else {
        const int atom = (blockIdx.x - PROJ_BLOCKS) * 4 + wave;

        float w[F_P];
        #pragma unroll
        for (int c = 0; c < F_P; ++c) w[c] = W_PA[c * H + h];
        const float bias = b_PA[h];

        const int start = row_start[atom];
        const int end   = row_start[atom + 1];

        float acc = 0.f;
        int p = start;
        for (; p + 4 <= end; p += 4) {
            f32x2 v[4][7];
            #pragma unroll
            for (int r = 0; r < 4; ++r) {
                const f32x2* src = (const f32x2*)(pf + (size_t)(p + r) * F_P);
                #pragma unroll
                for (int c = 0; c < 7; ++c) v[r][c] = __builtin_nontemporal_load(src + c);
            }
            #pragma unroll
            for (int r = 0; r < 4; ++r) {
                float s0 = bias;
                #pragma unroll
                for (int c = 0; c < 7; ++c) {
                    s0 = fmaf(v[r][c].x, w[2*c], s0);
                    s0 = fmaf(v[r][c].y, w[2*c+1], s0);
                }
                acc += fmaxf(s0, 0.f);
            }
        }
        for (; p < end; ++p) {
            const f32x2* src = (const f32x2*)(pf + (size_t)p * F_P);
            float s0 = bias;
            #pragma unroll
            for (int c = 0; c < 7; ++c) {
                f32x2 v = __builtin_nontemporal_load(src + c);
                s0 = fmaf(v.x, w[2*c], s0); s0 = fmaf(v.y, w[2*c+1], s0);
            }
            acc += fmaxf(s0, 0.f);
        }
        if (lane < H) PA[(size_t)atom * H + lane] = acc;
    }
}

// ================= stage 2 (fat): pair_out (MFMA, R7 loop, 5 blocks/CU) || atom_out =================
__global__ __launch_bounds__(256, 5) void k_stage2(
    const float* __restrict__ pf, const int* __restrict__ a2p,
    const unsigned short* __restrict__ X,
    const float* __restrict__ W_PP, const float* __restrict__ b_PP,
    const float* __restrict__ W_P, const float* __restrict__ b_P,
    const float* __restrict__ AA, const float* __restrict__ PA,
    const float* __restrict__ W_A, const float* __restrict__ b_A,
    float* __restrict__ outA, float* __restrict__ outP)
{
    __shared__ __align__(16) char smem[26624];

    const int tid  = threadIdx.x;
    const int wave = __builtin_amdgcn_readfirstlane(tid >> 6);
    const int lane = tid & 63;

    if (blockIdx.x < PO_BLOCKS) {
        uint4* sWf = (uint4*)smem;                                // 16 KB
        float (*sWPP)[64] = (float(*)[64])(smem + 16384);         // 3.5 KB
        float* sbPP = (float*)(smem + 16384 + 3584);              // 256 B
        float* sT   = (float*)(smem + 16384 + 3584 + 256);        // 4*400*4 = 6.4 KB

        // build B-frags (R3-validated): lane holds col=lane&15, k = s*32+(lane>>4)*8+[0..7]
        #pragma unroll
        for (int r = 0; r < 4; ++r) {
            int e = r * 256 + tid;
            int fid = e >> 6, lane_e = e & 63;
            int s_ = fid >> 2, n_ = fid & 3;
            int col_e = lane_e & 15, gg = lane_e >> 4;
            int k0 = s_ * 32 + gg * 8;
            int c = n_ * 16 + col_e;
            unsigned w[4];
            #pragma unroll
            for (int hh = 0; hh < 4; ++hh) {
                float vlo = 0.f, vhi = 0.f;
                if (c < H) {
                    int k = k0 + 2 * hh;
                    int r0 = (k < 64) ? (k < H ? k : -1) : ((k - 64) < H ? H + (k - 64) : -1);
                    int k2 = k + 1;
                    int r1 = (k2 < 64) ? (k2 < H ? k2 : -1) : ((k2 - 64) < H ? H + (k2 - 64) : -1);
                    if (r0 >= 0) vlo = W_P[r0 * H + c];
                    if (r1 >= 0) vhi = W_P[r1 * H + c];
                }
                w[hh] = (unsigned)f2bf(vlo) | ((unsigned)f2bf(vhi) << 16);
            }
            sWf[e] = make_uint4(w[0], w[1], w[2], w[3]);
        }
        for (int t = tid; t < F_P * 64; t += 256) {
            int c = t >> 6, o = t & 63;
            sWPP[c][o] = (o < H) ? W_PP[c * H + o] : 0.f;
        }
        if (tid < 64) sbPP[tid] = tid < H ? b_PP[tid] : 0.f;
        __syncthreads();

        const int col = lane & 15;
        const int g = lane >> 4;
        float* const myT = sT + wave * 400;

        float bP[4];
        #pragma unroll
        for (int n = 0; n < 4; ++n) {
            int c = n * 16 + col;
            bP[n] = (c < H) ? b_P[c] : 0.f;
        }

        const int NT = N_PAIRS / 16;     // 100000 tiles
        const int step = PO_BLOCKS * 4;  // 8192

        int t = blockIdx.x * 4 + wave;   // always < step <= NT
        int2 ij = ((const int2*)a2p)[t * 16 + col];
        while (t < NT) {
            const int t1 = t + step;
            int2 ij1 = ij;
            if (t1 < NT) ij1 = ((const int2*)a2p)[t1 * 16 + col];  // prefetch next tile's indices

            const int pairbase = t * 16;
            const unsigned short* Xi = X + (size_t)ij.x * 128;
            const unsigned short* Xj = X + (size_t)ij.y * 128;

            // issue all 8 gathers early (each 16B, lane owns its frag chunk)
            uint4 A1[2], B2[2], B1[2], A2[2];
            #pragma unroll
            for (int s = 0; s < 2; ++s) {
                int off = s * 32 + g * 8;
                A1[s] = *(const uint4*)(Xi + off);
                B2[s] = *(const uint4*)(Xj + 64 + off);
                B1[s] = *(const uint4*)(Xj + off);
                A2[s] = *(const uint4*)(Xi + 64 + off);
            }

            float pfr[F_P];
            {
                const f32x2* src = (const f32x2*)(pf + (size_t)(pairbase + col) * F_P);
                #pragma unroll
                for (int c = 0; c < 7; ++c) {
                    f32x2 v = __builtin_nontemporal_load(src + c);
                    pfr[2*c] = v.x; pfr[2*c+1] = v.y;
                }
            }

            f32x4 acc[4];
            #pragma unroll
            for (int n = 0; n < 4; ++n) acc[n] = (f32x4){bP[n], bP[n], bP[n], bP[n]};

            // ---- PP K-steps (global k = 64..127): overlaps gather latency ----
            #pragma unroll
            for (int s2 = 0; s2 < 2; ++s2) {
                int ob = s2 * 32 + g * 8;
                float pp[8];
                {
                    const f32x4* bb = (const f32x4*)&sbPP[ob];
                    f32x4 b0 = bb[0], b1 = bb[1];
                    pp[0]=b0.x; pp[1]=b0.y; pp[2]=b0.z; pp[3]=b0.w;
                    pp[4]=b1.x; pp[5]=b1.y; pp[6]=b1.z; pp[7]=b1.w;
                }
                #pragma unroll
                for (int c = 0; c < F_P; ++c) {
                    const f32x4* wr = (const f32x4*)&sWPP[c][ob];
                    f32x4 w0 = wr[0], w1 = wr[1];
                    float pc = pfr[c];
                    pp[0]=fmaf(pc,w0.x,pp[0]); pp[1]=fmaf(pc,w0.y,pp[1]);
                    pp[2]=fmaf(pc,w0.z,pp[2]); pp[3]=fmaf(pc,w0.w,pp[3]);
                    pp[4]=fmaf(pc,w1.x,pp[4]); pp[5]=fmaf(pc,w1.y,pp[5]);
                    pp[6]=fmaf(pc,w1.z,pp[6]); pp[7]=fmaf(pc,w1.w,pp[7]);
                }
                union { unsigned u[4]; bf16x8 v; } ap;
                #pragma unroll
                for (int hh = 0; hh < 4; ++hh) {
                    float lo = fmaxf(pp[2*hh], 0.f), hi2 = fmaxf(pp[2*hh+1], 0.f);
                    ap.u[hh] = (unsigned)f2bf(lo) | ((unsigned)f2bf(hi2) << 16);
                }
                int sg = 2 + s2;
                #pragma unroll
                for (int n = 0; n < 4; ++n) {
                    bf16x8 bfr = ((const bf16x8*)sWf)[(sg * 4 + n) * 64 + lane];
                    acc[n] = __builtin_amdgcn_mfma_f32_16x16x32_bf16(ap.v, bfr, acc[n], 0, 0, 0);
                }
            }

            // ---- AP K-steps (global k = 0..63); b_AP pre-folded into X1 ----
            #pragma unroll
            for (int s = 0; s < 2; ++s) {
                const unsigned* a1 = (const unsigned*)&A1[s];
                const unsigned* b2 = (const unsigned*)&B2[s];
                const unsigned* b1 = (const unsigned*)&B1[s];
                const unsigned* a2 = (const unsigned*)&A2[s];
                union { unsigned u[4]; bf16x8 v; } ap;
                #pragma unroll
                for (int hh = 0; hh < 4; ++hh) {
                    float e1l = bfu(a1[hh],0) + bfu(b2[hh],0);
                    float e2l = bfu(b1[hh],0) + bfu(a2[hh],0);
                    float apl = fmaxf(e1l, 0.f) + fmaxf(e2l, 0.f);
                    float e1h = bfu(a1[hh],1) + bfu(b2[hh],1);
                    float e2h = bfu(b1[hh],1) + bfu(a2[hh],1);
                    float aph = fmaxf(e1h, 0.f) + fmaxf(e2h, 0.f);
                    ap.u[hh] = (unsigned)f2bf(apl) | ((unsigned)f2bf(aph) << 16);
                }
                #pragma unroll
                for (int n = 0; n < 4; ++n) {
                    bf16x8 bfr = ((const bf16x8*)sWf)[(s * 4 + n) * 64 + lane];
                    acc[n] = __builtin_amdgcn_mfma_f32_16x16x32_bf16(ap.v, bfr, acc[n], 0, 0, 0);
                }
            }

            // ---- two-phase epilogue: rows 0..7 then 8..15 via 400-float wave buffer ----
            float* dst = outP + (size_t)pairbase * H;
            if (g < 2) {
                #pragma unroll
                for (int n = 0; n < 4; ++n) {
                    int c = n * 16 + col;
                    if (c < H) {
                        #pragma unroll
                        for (int q = 0; q < 4; ++q)
                            myT[(g * 4 + q) * H + c] = fmaxf(acc[n][q], 0.f);
                    }
                }
            }
            #pragma unroll
            for (int e = 0; e < 4; ++e) {
                int idx = e * 64 + lane;            // f32x2 idx, 200 total
                if (idx < 200) {
                    f32x2 v = *(const f32x2*)&myT[idx * 2];
                    *(f32x2*)(dst + idx * 2) = v;
                }
            }
            if (g >= 2) {
                #pragma unroll
                for (int n = 0; n < 4; ++n) {
                    int c = n * 16 + col;
                    if (c < H) {
                        #pragma unroll
                        for (int q = 0; q < 4; ++q)
                            myT[((g - 2) * 4 + q) * H + c] = fmaxf(acc[n][q], 0.f);
                    }
                }
            }
            #pragma unroll
            for (int e = 0; e < 4; ++e) {
                int idx = e * 64 + lane;
                if (idx < 200) {
                    f32x2 v = *(const f32x2*)&myT[idx * 2];
                    *(f32x2*)(dst + 400 + idx * 2) = v;
                }
            }

            ij = ij1;
            t = t1;
        }
    } else {
        // ---------------- atom_out ----------------
        float* sW = (float*)smem;            // 20 KB
        float* sb = (float*)(smem + 20000);  // 200 B
        for (int t = tid; t < 2 * H * H; t += 256) sW[t] = W_A[t];
        if (tid < H) sb[tid] = b_A[tid];
        __syncthreads();

        const int h = lane < H ? lane : 0;
        const int base = (blockIdx.x - PO_BLOCKS) * 32 + wave * 8;

        float acc[8];
        #pragma unroll
        for (int a = 0; a < 8; ++a) acc[a] = sb[h];

        for (int k = 0; k < H; ++k) {
            float wA = sW[k * H + h];
            float wP = sW[(H + k) * H + h];
            #pragma unroll
            for (int a = 0; a < 8; ++a) {
                acc[a] = fmaf(AA[(size_t)(base + a) * H + k], wA, acc[a]);
                acc[a] = fmaf(PA[(size_t)(base + a) * H + k], wP, acc[a]);
            }
        }
        #pragma unroll
        for (int a = 0; a < 8; ++a)
            if (lane < H) outA[(size_t)(base + a) * H + lane] = fmaxf(acc[a], 0.f);
    }
}

// ---------------- launcher ----------------
extern "C" void kernel_launch(void* const* d_in, const int* in_sizes, int n_in,
                              void* d_out, int out_size, void* d_ws, size_t ws_size,
                              hipStream_t stream) {
    const float* af    = (const float*)d_in[0];
    const float* pfeat = (const float*)d_in[1];
    const int*   split = (const int*)d_in[2];
    const int*   a2p   = (const int*)d_in[3];
    const float* W_AA  = (const float*)d_in[4];
    const float* b_AA  = (const float*)d_in[5];
    const float* W_PA  = (const float*)d_in[6];
    const float* b_PA  = (const float*)d_in[7];
    const float* W_A   = (const float*)d_in[8];
    const float* b_A   = (const float*)d_in[9];
    const float* W_AP  = (const float*)d_in[10];
    const float* b_AP  = (const float*)d_in[11];
    const float* W_PP  = (const float*)d_in[12];
    const float* b_PP  = (const float*)d_in[13];
    const float* W_P   = (const float*)d_in[14];
    const float* b_P   = (const float*)d_in[15];

    float* outA = (float*)d_out;
    float* outP = (float*)d_out + (size_t)N_ATOMS * H;

    unsigned short* X  = (unsigned short*)d_ws;               // 25.6 MB
    float* AA          = (float*)(X + (size_t)N_ATOMS * 128); // 20 MB
    float* PA          = AA + (size_t)N_ATOMS * H;            // 20 MB
    int*   row_start   = (int*)(PA + (size_t)N_ATOMS * H);    // (N_ATOMS+1)*4B

    k_row_starts<<<(N_PAIRS + 255) / 256, 256, 0, stream>>>(split, row_start);
    k_stage1<<<PROJ_BLOCKS + SEG_BLOCKS, 256, 0, stream>>>(
        af, W_AA, b_AA, W_AP, b_AP, pfeat, row_start, W_PA, b_PA, AA, X, PA);
    k_stage2<<<PO_BLOCKS + AOUT_BLOCKS, 256, 0, stream>>>(
        pfeat, a2p, X, W_PP, b_PP, W_P, b_P, AA, PA, W_A, b_A, outA, outP);
}